// Round 3
// baseline (86.027 us; speedup 1.0000x reference)
//
#include <hip/hip_runtime.h>
#include <hip/hip_bf16.h>

// NT-Xent loss, BS=4096, D=256, TAU=0.5.
// R17 = traffic + clean-occupancy attack on kgemm.
// Post-mortem R16: B0[4]+B1[4] both live = ~190 VGPR under a (256,3) cap
// -> spilled, so the 3-blocks/CU theory was never actually tested. R17:
//  (a) 4 sequential Gj-tiles per block share one staged A panel:
//      L2/L3 reads 133MB -> ~84MB (A: 66->17MB). 544 blocks.
//  (b) single B[4] buffer loaded per-K-half inside the loop:
//      acc 64 + B 64 + A 8 + addr ~ 155 VGPR -> (256,3) genuinely fits,
//      3 blocks/CU (12 waves/CU), LDS 96KB/CU.
// Theory: kgemm (~17.6us of the 27us pipeline) is L2/L3-traffic/latency
// bound (MFMA-halving R14 and spilled-occupancy R16 both null). Predict
// kgemm ~11-12us, total 76-78us. If null: isolation probe next round.
//
// znsw layout (fragment-native for mfma_scale_f32_16x16x128_f8f6f4,
// lane map: row = l&15, k = (l>>4)*32 + 0..31 per K=128 half):
//   16-row group rg (4096 B): piece pi (0..3) = h*2 + p (h = K-half,
//   p = 16-byte sub-piece): byte rg*4096 + pi*1024 + l*16 holds
//   row = rg*16 + (l&15), k = h*128 + (l>>4)*32 + p*16 + (0..15).
// A 128-row panel (8 rgs) = 32KB contiguous; staging stays 1:1 memcpy;
// all LDS/global fragment reads remain lane-contiguous 16B (conflict-free).

#define N_ROWS 8192
#define BSZ    4096
#define DIM    256
#define INV_TAU 2.0f
#define EPS_REF 1e-8f
#define COS_EPS 1e-8f
#define NG2     64                     // 128-row groups
#define NBLK    544                    // sum over Gi of ceil((64-Gi)/4)
#define LSTRIDE 260                    // padded floats per row in knorm LDS

typedef __attribute__((ext_vector_type(4))) float f32x4;
typedef __attribute__((ext_vector_type(8))) int   v8i;
typedef union { int4 x[2]; v8i v; } frag32;

// sum across each 16-lane group via DPP row_ror (VALU pipe, no LDS traffic)
__device__ __forceinline__ float red16(float x) {
    x += __int_as_float(__builtin_amdgcn_update_dpp(0, __float_as_int(x), 0x121, 0xf, 0xf, false));
    x += __int_as_float(__builtin_amdgcn_update_dpp(0, __float_as_int(x), 0x122, 0xf, 0xf, false));
    x += __int_as_float(__builtin_amdgcn_update_dpp(0, __float_as_int(x), 0x124, 0xf, 0xf, false));
    x += __int_as_float(__builtin_amdgcn_update_dpp(0, __float_as_int(x), 0x128, 0xf, 0xf, false));
    return x;
}

// ---------------- Kernel 1: normalize + fp8 quantize + MX-fragment swizzle --
__global__ __launch_bounds__(256) void knorm(const float* __restrict__ zi,
                                             const float* __restrict__ zj,
                                             unsigned char* __restrict__ znsw,
                                             float* __restrict__ out) {
    __shared__ float lds[16 * LSTRIDE];
    __shared__ float nrm[16];
    const int rg = blockIdx.x;     // 0..511: 16-row group
    const int t  = threadIdx.x;
    const int w  = t >> 6;
    const int l  = t & 63;
    const int row0 = rg * 16;
    if (rg == 0 && t == 0) out[0] = 0.f;    // kfinal atomics run after us

    // load + register norms: iteration s -> row 4s+w, cols l*4..l*4+3
    #pragma unroll
    for (int s = 0; s < 4; ++s) {
        const int row = s * 4 + w;
        const int r   = row0 + row;
        const float* src = (r < BSZ) ? zi + (size_t)r * DIM + l * 4
                                     : zj + (size_t)(r - BSZ) * DIM + l * 4;
        const float4 v = *(const float4*)src;
        *(float4*)&lds[row * LSTRIDE + l * 4] = v;
        float ss = v.x*v.x + v.y*v.y + v.z*v.z + v.w*v.w;
        #pragma unroll
        for (int off = 32; off >= 1; off >>= 1) ss += __shfl_xor(ss, off);
        if (l == 0) nrm[row] = 1.0f / fmaxf(sqrtf(ss), COS_EPS);
    }
    __syncthreads();

    // quantize: thread t -> piece pi = t>>6 (h = pi>>1, p = pi&1), lane fl.
    // 16 consecutive k starting at h*128 + (fl>>4)*32 + p*16, row fl&15.
    const int pi = t >> 6, fl = t & 63;
    const int h = pi >> 1, p = pi & 1;
    const int r16 = fl & 15, q = fl >> 4;
    const int k0 = h * 128 + q * 32 + p * 16;
    const float inv = nrm[r16];
    float f[16];
    #pragma unroll
    for (int j = 0; j < 16; ++j) f[j] = lds[r16 * LSTRIDE + k0 + j] * inv;
    int wd[4];
    #pragma unroll
    for (int g = 0; g < 4; ++g) {
        int a = 0;
        a = __builtin_amdgcn_cvt_pk_fp8_f32(f[g*4+0], f[g*4+1], a, false);
        a = __builtin_amdgcn_cvt_pk_fp8_f32(f[g*4+2], f[g*4+3], a, true);
        wd[g] = a;
    }
    *(int4*)(znsw + (size_t)rg * 4096 + pi * 1024 + fl * 16) =
        make_int4(wd[0], wd[1], wd[2], wd[3]);
}

// ---------------- Kernel 2: triangular Gram; A staged once per 4 tiles -----
__global__ __launch_bounds__(256, 3) void kgemm(const unsigned char* __restrict__ znsw,
                                                float* __restrict__ P,
                                                float* __restrict__ selfdot,
                                                float* __restrict__ pairdot) {
    __shared__ __align__(16) unsigned char pan[32768];   // A panel (all K)
    const int w = threadIdx.x >> 6;
    const int l = threadIdx.x & 63;

    // decode blockIdx -> (Gi, Gj0): row Gi has ceil((64-Gi)/4) blocks,
    // each covering tiles Gj = Gi + 4b .. Gi + 4b + 3 (clipped at 63).
    int t  = blockIdx.x;
    int Gi = 0;
    int cnt = 16;                          // ceil((64-0)/4)
    while (t >= cnt) { t -= cnt; ++Gi; cnt = (64 - Gi + 3) >> 2; }
    const int Gj0 = Gi + t * 4;

    // stage A panel (32KB): 1:1 contiguous copy, 8 issues/thread
    const char* srcA = (const char*)znsw + (size_t)Gi * 32768;
    #pragma unroll
    for (int sub = 0; sub < 8; ++sub) {
        const int off = sub * 4096 + w * 1024;
        __builtin_amdgcn_global_load_lds(
            (const __attribute__((address_space(1))) void*)(srcA + off + l * 16),
            (__attribute__((address_space(3))) void*)(&pan[off]), 16, 0, 0);
    }

    // quadrant: rows (w>>1)*64 of A, cols (w&1)*64 of B
    const int rh = w >> 1, ch = w & 1;
    const int c = l & 15, q = l >> 4;
    const int rsel = c - 4 * q;
    const bool vld = (rsel >= 0) && (rsel < 4);

    __syncthreads();   // A staged

    for (int jj = 0; jj < 4; ++jj) {
        const int Gj = Gj0 + jj;
        if (Gj > 63) break;

        // B fragment base for (nt, h, p): bbase + nt*4096 + h*2048 + p*1024
        const char* bbase = (const char*)znsw + (size_t)Gj * 32768 + ch * 16384 + l * 16;

        f32x4 acc[4][4];
        #pragma unroll
        for (int mt = 0; mt < 4; ++mt)
            #pragma unroll
            for (int nt = 0; nt < 4; ++nt)
                acc[mt][nt] = (f32x4){0.f, 0.f, 0.f, 0.f};

        #pragma unroll
        for (int h = 0; h < 2; ++h) {
            frag32 B[4];                    // single buffer: keeps VGPR <= (256,3) cap
            #pragma unroll
            for (int nt = 0; nt < 4; ++nt) {
                B[nt].x[0] = *(const int4*)(bbase + nt * 4096 + h * 2048);
                B[nt].x[1] = *(const int4*)(bbase + nt * 4096 + h * 2048 + 1024);
            }
            #pragma unroll
            for (int mt = 0; mt < 4; ++mt) {
                frag32 A;
                const char* ap = (const char*)&pan[(rh * 4 + mt) * 4096 + h * 2048] + l * 16;
                A.x[0] = *(const int4*)(ap);
                A.x[1] = *(const int4*)(ap + 1024);
                #pragma unroll
                for (int nt = 0; nt < 4; ++nt)
                    acc[mt][nt] = __builtin_amdgcn_mfma_scale_f32_16x16x128_f8f6f4(
                        A.v, B[nt].v, acc[mt][nt],
                        0, 0,                     // cbsz=0 (fp8 e4m3), blgp=0 (fp8)
                        0, 0x7f7f7f7f,            // scale_a opsel, e8m0 1.0
                        0, 0x7f7f7f7f);           // scale_b opsel, e8m0 1.0
            }
        }

        // ---- wave-local epilogue (C/D layout: col = l&15, row = (l>>4)*4+reg) ----
        // self/pair diagonals live in quadrants with rh==ch
        if ((Gi == Gj || Gj == Gi + 32) && rh == ch) {
            float dv[4];
            #pragma unroll
            for (int mt = 0; mt < 4; ++mt) {
                float d = acc[mt][mt][0];
                #pragma unroll
                for (int r = 1; r < 4; ++r)
                    if (rsel == r) d = acc[mt][mt][r];
                dv[mt] = d;
            }
            if (vld) {
                float* dst = (Gi == Gj) ? selfdot : pairdot;
                #pragma unroll
                for (int mt = 0; mt < 4; ++mt)
                    dst[Gi * 128 + rh * 64 + mt * 16 + c] = dv[mt];
            }
        }

        #pragma unroll
        for (int mt = 0; mt < 4; ++mt)
            #pragma unroll
            for (int nt = 0; nt < 4; ++nt)
                #pragma unroll
                for (int r = 0; r < 4; ++r)
                    acc[mt][nt][r] = __expf(acc[mt][nt][r] * INV_TAU);

        // row sums (DPP reduce across 16 col lanes) -> P[Gj*2+ch][...]
        float rs[4][4];
        #pragma unroll
        for (int mt = 0; mt < 4; ++mt)
            #pragma unroll
            for (int r = 0; r < 4; ++r)
                rs[mt][r] = red16(acc[mt][0][r] + acc[mt][1][r] + acc[mt][2][r] + acc[mt][3][r]);
        if (c == 0) {
            #pragma unroll
            for (int mt = 0; mt < 4; ++mt) {
                const f32x4 o4 = (f32x4){rs[mt][0], rs[mt][1], rs[mt][2], rs[mt][3]};
                __builtin_nontemporal_store(o4,
                    (f32x4*)&P[(size_t)(Gj * 2 + ch) * N_ROWS + Gi * 128 + rh * 64 + mt * 16 + q * 4]);
            }
        }

        // col sums (strictly-upper blocks) -> P[Gi*2+rh][Gj*128 + ch*64 + ...]
        if (Gi != Gj) {
            float cs[4];
            #pragma unroll
            for (int nt = 0; nt < 4; ++nt) {
                float s = 0.f;
                #pragma unroll
                for (int mt = 0; mt < 4; ++mt)
                    #pragma unroll
                    for (int r = 0; r < 4; ++r)
                        s += acc[mt][nt][r];
                s += __shfl_xor(s, 16);
                s += __shfl_xor(s, 32);
                cs[nt] = s;
            }
            if (q == 0) {
                #pragma unroll
                for (int nt = 0; nt < 4; ++nt)
                    __builtin_nontemporal_store(cs[nt],
                        &P[(size_t)(Gi * 2 + rh) * N_ROWS + Gj * 128 + ch * 64 + nt * 16 + c]);
            }
        }
    }
}

// ---------------- Kernel 3: per-row loss (latency-hiding) -------------------
__global__ __launch_bounds__(256) void kfinal(const float* __restrict__ P,
                                              const float* __restrict__ selfdot,
                                              const float* __restrict__ pairdot,
                                              float* __restrict__ out) {
    const int l = threadIdx.x & 63;        // row within block
    const int w = threadIdx.x >> 6;        // strip quarter
    const int row = blockIdx.x * 64 + l;
    float s = 0.f;
    #pragma unroll
    for (int st = 0; st < 32; ++st)
        s += P[(size_t)(w * 32 + st) * N_ROWS + row];
    __shared__ float wsum[4][64];
    wsum[w][l] = s;
    __syncthreads();
    if (w == 0) {
        const float tot = wsum[0][l] + wsum[1][l] + wsum[2][l] + wsum[3][l];
        const float selfe = __expf(selfdot[row] * INV_TAU);
        const float pd    = pairdot[(row < BSZ) ? row : row - BSZ];
        float loss = logf(tot - selfe + EPS_REF) - pd * INV_TAU;
        #pragma unroll
        for (int off = 32; off >= 1; off >>= 1) loss += __shfl_xor(loss, off);
        if (l == 0) atomicAdd(out, loss * (1.0f / (float)N_ROWS));
    }
}

extern "C" void kernel_launch(void* const* d_in, const int* in_sizes, int n_in,
                              void* d_out, int out_size, void* d_ws, size_t ws_size,
                              hipStream_t stream) {
    const float* zi = (const float*)d_in[0];
    const float* zj = (const float*)d_in[1];
    float* out = (float*)d_out;

    char* ws = (char*)d_ws;
    unsigned char* znsw = (unsigned char*)ws;                       // 2 MB
    float* P       = (float*)(ws + 2 * 1024 * 1024);                // 4 MB
    float* selfdot = (float*)(ws + 6 * 1024 * 1024);                // 32 KB
    float* pairdot = (float*)(ws + 6 * 1024 * 1024 + 32 * 1024);    // 16 KB

    knorm <<<N_ROWS / 16, 256, 0, stream>>>(zi, zj, znsw, out);
    kgemm <<<NBLK, 256, 0, stream>>>(znsw, P, selfdot, pairdot);
    kfinal<<<N_ROWS / 64, 256, 0, stream>>>(P, selfdot, pairdot, out);
}

// Round 4
// 82.868 us; speedup vs baseline: 1.0381x; 1.0381x over previous
//
#include <hip/hip_runtime.h>
#include <hip/hip_bf16.h>

// NT-Xent loss, BS=4096, D=256, TAU=0.5.
// R18 = clean occupancy test: R14's known-good 2080-block structure with
// ONLY the VGPR diet applied. History: R14 (MFMA halving) null; R16
// (occupancy) invalid -- B0+B1 live = ~190 VGPR spilled under (256,3);
// R17 (traffic -37%, 544 blocks x 4-tile serial) REGRESSED to 86 ->
// kgemm is latency/parallelism-bound, not traffic- or MFMA-bound.
// R18: single B[4] buffer (h=1 loaded in-loop), A read per-mt from LDS
// (8 regs), acc 64 + B 32 + A 8 + addr ~25 = ~130 VGPR < 170 cap of
// __launch_bounds__(256,3) -> genuinely 3 blocks/CU (12 waves/CU).
// Predict kgemm 17.6 -> ~13us, total 78-80. Null => occupancy is not the
// lever; next round = persistent/cooperative fusion (kill launch gaps +
// epilogue off critical path).
//
// znsw layout (fragment-native for mfma_scale_f32_16x16x128_f8f6f4,
// lane map: row = l&15, k = (l>>4)*32 + 0..31 per K=128 half):
//   16-row group rg (4096 B): piece pi (0..3) = h*2 + p (h = K-half,
//   p = 16-byte sub-piece): byte rg*4096 + pi*1024 + l*16 holds
//   row = rg*16 + (l&15), k = h*128 + (l>>4)*32 + p*16 + (0..15).
// A 128-row panel (8 rgs) = 32KB contiguous; staging stays 1:1 memcpy;
// all LDS/global fragment reads remain lane-contiguous 16B (conflict-free).

#define N_ROWS 8192
#define BSZ    4096
#define DIM    256
#define INV_TAU 2.0f
#define EPS_REF 1e-8f
#define COS_EPS 1e-8f
#define NG2     64                     // 128-row groups
#define NTILES  (NG2 * (NG2 + 1) / 2)  // 2080 triangular tiles
#define LSTRIDE 260                    // padded floats per row in knorm LDS

typedef __attribute__((ext_vector_type(4))) float f32x4;
typedef __attribute__((ext_vector_type(8))) int   v8i;
typedef union { int4 x[2]; v8i v; } frag32;

// sum across each 16-lane group via DPP row_ror (VALU pipe, no LDS traffic)
__device__ __forceinline__ float red16(float x) {
    x += __int_as_float(__builtin_amdgcn_update_dpp(0, __float_as_int(x), 0x121, 0xf, 0xf, false));
    x += __int_as_float(__builtin_amdgcn_update_dpp(0, __float_as_int(x), 0x122, 0xf, 0xf, false));
    x += __int_as_float(__builtin_amdgcn_update_dpp(0, __float_as_int(x), 0x124, 0xf, 0xf, false));
    x += __int_as_float(__builtin_amdgcn_update_dpp(0, __float_as_int(x), 0x128, 0xf, 0xf, false));
    return x;
}

// ---------------- Kernel 1: normalize + fp8 quantize + MX-fragment swizzle --
__global__ __launch_bounds__(256) void knorm(const float* __restrict__ zi,
                                             const float* __restrict__ zj,
                                             unsigned char* __restrict__ znsw,
                                             float* __restrict__ out) {
    __shared__ float lds[16 * LSTRIDE];
    __shared__ float nrm[16];
    const int rg = blockIdx.x;     // 0..511: 16-row group
    const int t  = threadIdx.x;
    const int w  = t >> 6;
    const int l  = t & 63;
    const int row0 = rg * 16;
    if (rg == 0 && t == 0) out[0] = 0.f;    // kfinal atomics run after us

    // load + register norms: iteration s -> row 4s+w, cols l*4..l*4+3
    #pragma unroll
    for (int s = 0; s < 4; ++s) {
        const int row = s * 4 + w;
        const int r   = row0 + row;
        const float* src = (r < BSZ) ? zi + (size_t)r * DIM + l * 4
                                     : zj + (size_t)(r - BSZ) * DIM + l * 4;
        const float4 v = *(const float4*)src;
        *(float4*)&lds[row * LSTRIDE + l * 4] = v;
        float ss = v.x*v.x + v.y*v.y + v.z*v.z + v.w*v.w;
        #pragma unroll
        for (int off = 32; off >= 1; off >>= 1) ss += __shfl_xor(ss, off);
        if (l == 0) nrm[row] = 1.0f / fmaxf(sqrtf(ss), COS_EPS);
    }
    __syncthreads();

    // quantize: thread t -> piece pi = t>>6 (h = pi>>1, p = pi&1), lane fl.
    // 16 consecutive k starting at h*128 + (fl>>4)*32 + p*16, row fl&15.
    const int pi = t >> 6, fl = t & 63;
    const int h = pi >> 1, p = pi & 1;
    const int r16 = fl & 15, q = fl >> 4;
    const int k0 = h * 128 + q * 32 + p * 16;
    const float inv = nrm[r16];
    float f[16];
    #pragma unroll
    for (int j = 0; j < 16; ++j) f[j] = lds[r16 * LSTRIDE + k0 + j] * inv;
    int wd[4];
    #pragma unroll
    for (int g = 0; g < 4; ++g) {
        int a = 0;
        a = __builtin_amdgcn_cvt_pk_fp8_f32(f[g*4+0], f[g*4+1], a, false);
        a = __builtin_amdgcn_cvt_pk_fp8_f32(f[g*4+2], f[g*4+3], a, true);
        wd[g] = a;
    }
    *(int4*)(znsw + (size_t)rg * 4096 + pi * 1024 + fl * 16) =
        make_int4(wd[0], wd[1], wd[2], wd[3]);
}

// ---------------- Kernel 2: triangular Gram; A staged, B direct, MX MFMA ----
__global__ __launch_bounds__(256, 3) void kgemm(const unsigned char* __restrict__ znsw,
                                                float* __restrict__ P,
                                                float* __restrict__ selfdot,
                                                float* __restrict__ pairdot) {
    __shared__ __align__(16) unsigned char pan[32768];   // A panel (all K)
    const int w = threadIdx.x >> 6;
    const int l = threadIdx.x & 63;

    // triangular decode over NG2=64: S(G) = G*(129-G)/2
    const int t = blockIdx.x;
    int Gi = (int)((129.0f - sqrtf(16641.0f - 8.0f * (float)t)) * 0.5f);
    while ((Gi + 1) * (129 - (Gi + 1)) / 2 <= t) ++Gi;
    while (Gi * (129 - Gi) / 2 > t) --Gi;
    const int Gj = Gi + (t - Gi * (129 - Gi) / 2);

    // stage A panel (32KB): 1:1 contiguous copy, 8 issues/thread
    const char* srcA = (const char*)znsw + (size_t)Gi * 32768;
    #pragma unroll
    for (int sub = 0; sub < 8; ++sub) {
        const int off = sub * 4096 + w * 1024;
        __builtin_amdgcn_global_load_lds(
            (const __attribute__((address_space(1))) void*)(srcA + off + l * 16),
            (__attribute__((address_space(3))) void*)(&pan[off]), 16, 0, 0);
    }

    // quadrant: rows (w>>1)*64 of A, cols (w&1)*64 of B
    const int rh = w >> 1, ch = w & 1;
    // B fragment global base for (nt, h, p): bbase + nt*4096 + h*2048 + p*1024
    const char* bbase = (const char*)znsw + (size_t)Gj * 32768 + ch * 16384 + l * 16;

    // prefetch h=0 B fragments before the barrier (drain together with A)
    frag32 B[4];
    #pragma unroll
    for (int nt = 0; nt < 4; ++nt) {
        B[nt].x[0] = *(const int4*)(bbase + nt * 4096);
        B[nt].x[1] = *(const int4*)(bbase + nt * 4096 + 1024);
    }

    f32x4 acc[4][4];
    #pragma unroll
    for (int mt = 0; mt < 4; ++mt)
        #pragma unroll
        for (int nt = 0; nt < 4; ++nt)
            acc[mt][nt] = (f32x4){0.f, 0.f, 0.f, 0.f};

    __syncthreads();   // A staged; h=0 B in flight drained here too

    #pragma unroll
    for (int h = 0; h < 2; ++h) {
        if (h == 1) {   // reload same buffer with second K-half (exposed
                        // ~L2 latency once; hidden by 12 waves/CU)
            #pragma unroll
            for (int nt = 0; nt < 4; ++nt) {
                B[nt].x[0] = *(const int4*)(bbase + nt * 4096 + 2048);
                B[nt].x[1] = *(const int4*)(bbase + nt * 4096 + 3072);
            }
        }
        #pragma unroll
        for (int mt = 0; mt < 4; ++mt) {
            frag32 A;   // per-mt LDS read: 8 VGPRs live instead of 32
            const char* ap = (const char*)&pan[(rh * 4 + mt) * 4096 + h * 2048] + l * 16;
            A.x[0] = *(const int4*)(ap);
            A.x[1] = *(const int4*)(ap + 1024);
            #pragma unroll
            for (int nt = 0; nt < 4; ++nt)
                acc[mt][nt] = __builtin_amdgcn_mfma_scale_f32_16x16x128_f8f6f4(
                    A.v, B[nt].v, acc[mt][nt],
                    0, 0,                     // cbsz=0 (fp8 e4m3), blgp=0 (fp8)
                    0, 0x7f7f7f7f,            // scale_a opsel, e8m0 1.0
                    0, 0x7f7f7f7f);           // scale_b opsel, e8m0 1.0
        }
    }

    // ---- wave-local epilogue (C/D layout: col = l&15, row = (l>>4)*4+reg) ----
    const int c = l & 15, q = l >> 4;
    const int rsel = c - 4 * q;
    const bool vld = (rsel >= 0) && (rsel < 4);

    // self/pair diagonals live in quadrants with rh==ch
    if ((Gi == Gj || Gj == Gi + 32) && rh == ch) {
        float dv[4];
        #pragma unroll
        for (int mt = 0; mt < 4; ++mt) {
            float d = acc[mt][mt][0];
            #pragma unroll
            for (int r = 1; r < 4; ++r)
                if (rsel == r) d = acc[mt][mt][r];
            dv[mt] = d;
        }
        if (vld) {
            float* dst = (Gi == Gj) ? selfdot : pairdot;
            #pragma unroll
            for (int mt = 0; mt < 4; ++mt)
                dst[Gi * 128 + rh * 64 + mt * 16 + c] = dv[mt];
        }
    }

    #pragma unroll
    for (int mt = 0; mt < 4; ++mt)
        #pragma unroll
        for (int nt = 0; nt < 4; ++nt)
            #pragma unroll
            for (int r = 0; r < 4; ++r)
                acc[mt][nt][r] = __expf(acc[mt][nt][r] * INV_TAU);

    // row sums (DPP reduce across 16 col lanes) -> P[Gj*2+ch][...]
    float rs[4][4];
    #pragma unroll
    for (int mt = 0; mt < 4; ++mt)
        #pragma unroll
        for (int r = 0; r < 4; ++r)
            rs[mt][r] = red16(acc[mt][0][r] + acc[mt][1][r] + acc[mt][2][r] + acc[mt][3][r]);
    if (c == 0) {
        #pragma unroll
        for (int mt = 0; mt < 4; ++mt) {
            const f32x4 o4 = (f32x4){rs[mt][0], rs[mt][1], rs[mt][2], rs[mt][3]};
            __builtin_nontemporal_store(o4,
                (f32x4*)&P[(size_t)(Gj * 2 + ch) * N_ROWS + Gi * 128 + rh * 64 + mt * 16 + q * 4]);
        }
    }

    // col sums (strictly-upper blocks) -> P[Gi*2+rh][Gj*128 + ch*64 + ...]
    if (Gi != Gj) {
        float cs[4];
        #pragma unroll
        for (int nt = 0; nt < 4; ++nt) {
            float s = 0.f;
            #pragma unroll
            for (int mt = 0; mt < 4; ++mt)
                #pragma unroll
                for (int r = 0; r < 4; ++r)
                    s += acc[mt][nt][r];
            s += __shfl_xor(s, 16);
            s += __shfl_xor(s, 32);
            cs[nt] = s;
        }
        if (q == 0) {
            #pragma unroll
            for (int nt = 0; nt < 4; ++nt)
                __builtin_nontemporal_store(cs[nt],
                    &P[(size_t)(Gi * 2 + rh) * N_ROWS + Gj * 128 + ch * 64 + nt * 16 + c]);
        }
    }
}

// ---------------- Kernel 3: per-row loss (latency-hiding) -------------------
__global__ __launch_bounds__(256) void kfinal(const float* __restrict__ P,
                                              const float* __restrict__ selfdot,
                                              const float* __restrict__ pairdot,
                                              float* __restrict__ out) {
    const int l = threadIdx.x & 63;        // row within block
    const int w = threadIdx.x >> 6;        // strip quarter
    const int row = blockIdx.x * 64 + l;
    float s = 0.f;
    #pragma unroll
    for (int st = 0; st < 32; ++st)
        s += P[(size_t)(w * 32 + st) * N_ROWS + row];
    __shared__ float wsum[4][64];
    wsum[w][l] = s;
    __syncthreads();
    if (w == 0) {
        const float tot = wsum[0][l] + wsum[1][l] + wsum[2][l] + wsum[3][l];
        const float selfe = __expf(selfdot[row] * INV_TAU);
        const float pd    = pairdot[(row < BSZ) ? row : row - BSZ];
        float loss = logf(tot - selfe + EPS_REF) - pd * INV_TAU;
        #pragma unroll
        for (int off = 32; off >= 1; off >>= 1) loss += __shfl_xor(loss, off);
        if (l == 0) atomicAdd(out, loss * (1.0f / (float)N_ROWS));
    }
}

extern "C" void kernel_launch(void* const* d_in, const int* in_sizes, int n_in,
                              void* d_out, int out_size, void* d_ws, size_t ws_size,
                              hipStream_t stream) {
    const float* zi = (const float*)d_in[0];
    const float* zj = (const float*)d_in[1];
    float* out = (float*)d_out;

    char* ws = (char*)d_ws;
    unsigned char* znsw = (unsigned char*)ws;                       // 2 MB
    float* P       = (float*)(ws + 2 * 1024 * 1024);                // 4 MB
    float* selfdot = (float*)(ws + 6 * 1024 * 1024);                // 32 KB
    float* pairdot = (float*)(ws + 6 * 1024 * 1024 + 32 * 1024);    // 16 KB

    knorm <<<N_ROWS / 16, 256, 0, stream>>>(zi, zj, znsw, out);
    kgemm <<<NTILES, 256, 0, stream>>>(znsw, P, selfdot, pairdot);
    kfinal<<<N_ROWS / 64, 256, 0, stream>>>(P, selfdot, pairdot, out);
}